// Round 4
// baseline (287.764 us; speedup 1.0000x reference)
//
#include <hip/hip_runtime.h>
#include <hip/hip_bf16.h>

typedef float v2f __attribute__((ext_vector_type(2)));
typedef float v4f __attribute__((ext_vector_type(4)));

#define BATCH 4096
#define NF 26
#define NV 100000
#define ND_ 16      // embedding dim D
#define NA 16       // attention dim A
#define NDENSE 13
#define NPAIR 325   // NF*(NF-1)/2
#define ROWP 20     // padded LDS row stride in floats (80B)
#define WPB 4       // waves per block
#define BLOCK (WPB * 64)
#define CHUNK 21    // ceil(325/16) pairs per q-lane
#define REPS 16     // DIAGNOSTIC: repeat body to amortize fixed overhead + surface counters

static __device__ __forceinline__ v2f pk_fma(v2f a, v2f b, v2f c) {
    v2f d;
    asm("v_pk_fma_f32 %0, %1, %2, %3" : "=v"(d) : "v"(a), "v"(b), "v"(c));
    return d;
}
static __device__ __forceinline__ v2f pk_mul(v2f a, v2f b) {
    v2f d;
    asm("v_pk_mul_f32 %0, %1, %2" : "=v"(d) : "v"(a), "v"(b));
    return d;
}

__global__ __launch_bounds__(BLOCK, 4) void afm_kernel(
    const float* __restrict__ dense,     // [B, 13]
    const int*   __restrict__ sparse,    // [B, 26]
    const float* __restrict__ tables,    // [26, 100000, 16]
    const float* __restrict__ attW,      // [16, 16] row-major [d][k]
    const float* __restrict__ attB,      // [16]
    const float* __restrict__ attH,      // [16]
    const float* __restrict__ attP,      // [16]
    const float* __restrict__ wDense,    // [13]
    const float* __restrict__ wSparse,   // [416]
    const float* __restrict__ linB,      // [1]
    float* __restrict__ out)             // [B]
{
    __shared__ float sWT[NA * ND_];      // W transposed: sWT[col*16 + d]
    __shared__ __align__(16) float sEmb[WPB][NF * ROWP];
    __shared__ int sIdx[WPB][NF];

    const int tid  = threadIdx.x;
    const int wave = tid >> 6;
    const int lane = tid & 63;
    const int g    = lane >> 4;   // k-group: columns 4g..4g+3
    const int q    = lane & 15;   // pair-slot
    const int b    = blockIdx.x * WPB + wave;

    // ---- stage W transposed (one-time) + this wave's sparse indices ----
    sWT[(tid & 15) * ND_ + (tid >> 4)] = attW[tid];   // attW[d][k] -> sWT[k][d]
    if (lane < NF) sIdx[wave][lane] = sparse[b * NF + lane];
    __syncthreads();

    // ---- per-lane packed weights: W2[c][dp] = {W[2dp][4g+c], W[2dp+1][4g+c]} ----
    v2f W2[4][8];
    #pragma unroll
    for (int c = 0; c < 4; ++c) {
        const float* wc = &sWT[(4 * g + c) * ND_];
        #pragma unroll
        for (int dp = 0; dp < 8; ++dp)
            W2[c][dp] = *reinterpret_cast<const v2f*>(wc + 2 * dp);
    }
    v2f P2[8];
    #pragma unroll
    for (int dp = 0; dp < 8; ++dp)
        P2[dp] = *reinterpret_cast<const v2f*>(attP + 2 * dp);
    const float4 bv = *reinterpret_cast<const float4*>(attB + 4 * g);
    const float4 hv = *reinterpret_cast<const float4*>(attH + 4 * g);
    const float bvv[4] = {bv.x, bv.y, bv.z, bv.w};
    const float hvv[4] = {hv.x, hv.y, hv.z, hv.w};

    // init (i, j) for pair p0 (once; loop restores state each rep)
    const int p0  = q * CHUNK;
    int cnt = NPAIR - p0; cnt = cnt > CHUNK ? CHUNK : cnt;
    int i0 = 0, rem = p0;
    while (rem >= NF - 1 - i0) { rem -= NF - 1 - i0; ++i0; }
    const int j0 = i0 + 1 + rem;

    for (int rep = 0; rep < REPS; ++rep) {
        // force genuine re-execution of everything below each rep
        asm volatile("" ::: "memory");

        // ---- gather embeddings into padded LDS rows (wave-private) ----
        for (int c = lane; c < (NF * ND_) / 4; c += 64) {
            const int f  = c >> 2;
            const int d4 = (c & 3) << 2;
            const float4 v = *reinterpret_cast<const float4*>(
                tables + ((size_t)f * NV + (size_t)sIdx[wave][f]) * ND_ + d4);
            *reinterpret_cast<float4*>(&sEmb[wave][f * ROWP + d4]) = v;
        }
        __syncthreads();

        const float* __restrict__ semb = sEmb[wave];

        // ---- linear term ----
        float lin = 0.f;
        for (int e = lane; e < NF * ND_; e += 64)
            lin += semb[(e >> 4) * ROWP + (e & 15)] * wSparse[e];
        if (lane < NDENSE)
            lin += dense[b * NDENSE + lane] * wDense[lane];

        // ---- main pair loop ----
        int i = i0, j = j0;
        int ioff = i0 * ROWP, joff = j0 * ROWP;
        float num = 0.f, den = 0.f;

        for (int it = 0; it < CHUNK; ++it) {
            const float* ri = semb + ioff;
            const float* rj = semb + joff;

            v2f dp2 = {0.f, 0.f};
            v2f z2[4];
            #pragma unroll
            for (int c = 0; c < 4; ++c) z2[c] = (v2f){0.f, 0.f};

            #pragma unroll
            for (int c4 = 0; c4 < 4; ++c4) {
                const v4f a = *reinterpret_cast<const v4f*>(ri + 4 * c4);
                const v4f e = *reinterpret_cast<const v4f*>(rj + 4 * c4);
                const v2f ew0 = pk_mul(__builtin_shufflevector(a, a, 0, 1),
                                       __builtin_shufflevector(e, e, 0, 1));
                const v2f ew1 = pk_mul(__builtin_shufflevector(a, a, 2, 3),
                                       __builtin_shufflevector(e, e, 2, 3));
                dp2 = pk_fma(ew0, P2[2 * c4 + 0], dp2);
                dp2 = pk_fma(ew1, P2[2 * c4 + 1], dp2);
                #pragma unroll
                for (int c = 0; c < 4; ++c) {
                    z2[c] = pk_fma(ew0, W2[c][2 * c4 + 0], z2[c]);
                    z2[c] = pk_fma(ew1, W2[c][2 * c4 + 1], z2[c]);
                }
            }

            float s = 0.f;
            #pragma unroll
            for (int c = 0; c < 4; ++c) {
                const float z = z2[c].x + z2[c].y + bvv[c];
                s = fmaf(fmaxf(z, 0.f), hvv[c], s);
            }
            s += __shfl_xor(s, 16);
            s += __shfl_xor(s, 32);

            const float ev = (it < cnt) ? __expf(s) : 0.f;
            const float dp = dp2.x + dp2.y;
            num = fmaf(ev, dp, num);
            den += ev;

            ++j; joff += ROWP;
            if (j >= NF) {
                if (i < NF - 2) { ++i; ioff += ROWP; }
                j = i + 1; joff = ioff + ROWP;
            }
        }

        #pragma unroll
        for (int o = 32; o; o >>= 1) {
            num += __shfl_xor(num, o);
            den += __shfl_xor(den, o);
            lin += __shfl_xor(lin, o);
        }
        if (rep == REPS - 1 && lane == 0) {
            const float x = num / den + lin + linB[0];
            out[b] = 1.f / (1.f + __expf(-x));
        }
        __syncthreads();
    }
}

extern "C" void kernel_launch(void* const* d_in, const int* in_sizes, int n_in,
                              void* d_out, int out_size, void* d_ws, size_t ws_size,
                              hipStream_t stream) {
    const float* dense   = (const float*)d_in[0];
    const int*   sparse  = (const int*)d_in[1];
    const float* tables  = (const float*)d_in[2];
    const float* attW    = (const float*)d_in[3];
    const float* attB    = (const float*)d_in[4];
    const float* attH    = (const float*)d_in[5];
    const float* attP    = (const float*)d_in[6];
    const float* wDense  = (const float*)d_in[7];
    const float* wSparse = (const float*)d_in[8];
    const float* linB    = (const float*)d_in[9];
    float* out = (float*)d_out;

    const int grid = BATCH / WPB;  // 1024 blocks
    afm_kernel<<<grid, BLOCK, 0, stream>>>(
        dense, sparse, tables, attW, attB, attH, attP,
        wDense, wSparse, linB, out);
}

// Round 5
// 15.410 us; speedup vs baseline: 18.6738x; 18.6738x over previous
//
#include <hip/hip_runtime.h>
#include <hip/hip_bf16.h>

typedef float v4f    __attribute__((ext_vector_type(4)));
typedef float f32x16 __attribute__((ext_vector_type(16)));
typedef __bf16 bf16x8 __attribute__((ext_vector_type(8)));

#define BATCH 4096
#define NF 26
#define NV 100000
#define ND_ 16      // embedding dim D (= MFMA K)
#define NA 16       // attention dim A
#define NDENSE 13
#define NPAIR 325   // NF*(NF-1)/2
#define ROWP 20     // padded LDS row stride in floats (80B)
#define WPB 4       // waves per block, 1 item per wave
#define BLOCK (WPB * 64)
#define NTILE 11    // ceil(325/32) MFMA tiles per item

__global__ __launch_bounds__(BLOCK) void afm_kernel(
    const float* __restrict__ dense,     // [B, 13]
    const int*   __restrict__ sparse,    // [B, 26]
    const float* __restrict__ tables,    // [26, 100000, 16]
    const float* __restrict__ attW,      // [16, 16] row-major [d][k]
    const float* __restrict__ attB,      // [16]
    const float* __restrict__ attH,      // [16]
    const float* __restrict__ attP,      // [16]
    const float* __restrict__ wDense,    // [13]
    const float* __restrict__ wSparse,   // [416]
    const float* __restrict__ linB,      // [1]
    float* __restrict__ out)             // [B]
{
    __shared__ int sOFF[NPAIR];                       // (i*ROWP) | (j*ROWP)<<16
    __shared__ __align__(16) float sEmb[WPB][NF * ROWP];
    __shared__ int sIdx[WPB][NF];

    const int tid  = threadIdx.x;
    const int wave = tid >> 6;
    const int lane = tid & 63;
    const int col  = lane & 31;   // MFMA M/N index (pair slot within tile)
    const int hi   = lane >> 5;   // K-half: this lane supplies k = hi*8 .. hi*8+7
    const int b    = blockIdx.x * WPB + wave;

    // ---- pair offset table (block-shared, one-time) ----
    for (int p = tid; p < NPAIR; p += BLOCK) {
        int i = 0, rem = p;
        while (rem >= NF - 1 - i) { rem -= NF - 1 - i; ++i; }
        const int j = i + 1 + rem;
        sOFF[p] = (i * ROWP) | ((j * ROWP) << 16);
    }
    if (lane < NF) sIdx[wave][lane] = sparse[b * NF + lane];
    __syncthreads();   // sOFF is cross-wave; sIdx/sEmb are wave-private

    // ---- gather embeddings into padded LDS rows (wave-private region) ----
    for (int c = lane; c < (NF * ND_) / 4; c += 64) {
        const int f  = c >> 2;
        const int d4 = (c & 3) << 2;
        const float4 v = *reinterpret_cast<const float4*>(
            tables + ((size_t)f * NV + (size_t)sIdx[wave][f]) * ND_ + d4);
        *reinterpret_cast<float4*>(&sEmb[wave][f * ROWP + d4]) = v;
    }

    // ---- A-fragment: rows 0..15 = W^T (A[m][d] = W[d][m]), row 16 = att_p ----
    // lane: row m = col, k-slice d = hi*8 + t
    bf16x8 afrag;
    #pragma unroll
    for (int t = 0; t < 8; ++t) {
        float a = 0.f;
        if (col < NA)       a = attW[(hi * 8 + t) * NA + col];
        else if (col == NA) a = attP[hi * 8 + t];
        afrag[t] = (__bf16)a;
    }
    // per-lane post weights: acc reg r (r=0..7) holds z-row k=(r&3)+8*(r>>2)+4*hi
    float  hreg[8];
    f32x16 cinit = {0.f,0.f,0.f,0.f,0.f,0.f,0.f,0.f,0.f,0.f,0.f,0.f,0.f,0.f,0.f,0.f};
    #pragma unroll
    for (int r = 0; r < 8; ++r) {
        const int k = (r & 3) + 8 * (r >> 2) + 4 * hi;
        hreg[r]  = attH[k];
        cinit[r] = attB[k];    // bias folded into MFMA C-input
    }

    const float* __restrict__ semb = sEmb[wave];

    // ---- linear term (fp32): sparse_concat @ w_sparse + dense @ w_dense ----
    float lin = 0.f;
    for (int e = lane; e < NF * ND_; e += 64)
        lin += semb[(e >> 4) * ROWP + (e & 15)] * wSparse[e];
    if (lane < NDENSE)
        lin += dense[b * NDENSE + lane] * wDense[lane];

    // ---- MFMA tile loop: 32 pairs per tile ----
    float num = 0.f, den = 0.f;
    for (int t = 0; t < NTILE; ++t) {
        const int p     = t * 32 + col;
        const bool valid = (p < NPAIR) && (hi == 0);
        const int pc    = (p < NPAIR) ? p : (NPAIR - 1);
        const int offs  = sOFF[pc];
        const float* ri = semb + (offs & 0xffff) + hi * 8;
        const float* rj = semb + (offs >> 16)    + hi * 8;

        const v4f x0 = *reinterpret_cast<const v4f*>(ri);
        const v4f x1 = *reinterpret_cast<const v4f*>(ri + 4);
        const v4f y0 = *reinterpret_cast<const v4f*>(rj);
        const v4f y1 = *reinterpret_cast<const v4f*>(rj + 4);
        const v4f e0 = x0 * y0;      // 2x v_pk_mul_f32
        const v4f e1 = x1 * y1;

        bf16x8 bfrag;                 // B[k=hi*8+t][col] = EWP[pair][d]
        bfrag[0] = (__bf16)e0[0]; bfrag[1] = (__bf16)e0[1];
        bfrag[2] = (__bf16)e0[2]; bfrag[3] = (__bf16)e0[3];
        bfrag[4] = (__bf16)e1[0]; bfrag[5] = (__bf16)e1[1];
        bfrag[6] = (__bf16)e1[2]; bfrag[7] = (__bf16)e1[3];

        const f32x16 acc =
            __builtin_amdgcn_mfma_f32_32x32x16_bf16(afrag, bfrag, cinit, 0, 0, 0);

        // score partial over this lane's 8 z-rows; row 16 (dp) sits in acc[8] for hi=0
        float sp = 0.f;
        #pragma unroll
        for (int r = 0; r < 8; ++r)
            sp = fmaf(fmaxf(acc[r], 0.f), hreg[r], sp);
        const float sfull = sp + __shfl_xor(sp, 32);

        // scores are O(1e-5): exp without max-subtraction is exact-safe
        const float ev = valid ? __expf(sfull) : 0.f;
        num = fmaf(ev, acc[8], num);
        den += ev;
    }

    // ---- wave-reduce num/den/lin, finalize ----
    #pragma unroll
    for (int o = 32; o; o >>= 1) {
        num += __shfl_xor(num, o);
        den += __shfl_xor(den, o);
        lin += __shfl_xor(lin, o);
    }
    if (lane == 0) {
        const float x = num / den + lin + linB[0];
        out[b] = 1.f / (1.f + __expf(-x));
    }
}

extern "C" void kernel_launch(void* const* d_in, const int* in_sizes, int n_in,
                              void* d_out, int out_size, void* d_ws, size_t ws_size,
                              hipStream_t stream) {
    const float* dense   = (const float*)d_in[0];
    const int*   sparse  = (const int*)d_in[1];
    const float* tables  = (const float*)d_in[2];
    const float* attW    = (const float*)d_in[3];
    const float* attB    = (const float*)d_in[4];
    const float* attH    = (const float*)d_in[5];
    const float* attP    = (const float*)d_in[6];
    const float* wDense  = (const float*)d_in[7];
    const float* wSparse = (const float*)d_in[8];
    const float* linB    = (const float*)d_in[9];
    float* out = (float*)d_out;

    const int grid = BATCH / WPB;  // 1024 blocks, 1 wave per batch item
    afm_kernel<<<grid, BLOCK, 0, stream>>>(
        dense, sparse, tables, attW, attB, attH, attP,
        wDense, wSparse, linB, out);
}